// Round 24
// baseline (156.852 us; speedup 1.0000x reference)
//
#include <hip/hip_runtime.h>
#include <math.h>
#include <stdint.h>

#define CIN   16
#define COUT  64
#define H     256
#define W     256
#define OH    254
#define OW    254
#define HWSZ  (H * W)
#define FR    8          // f32 ring slots (rows)
#define HRN   8          // f16 ring slots (rows)
#define NT    64         // 2-row tiles per block

typedef _Float16 f16x8  __attribute__((ext_vector_type(8)));
typedef float    f32x16 __attribute__((ext_vector_type(16)));
typedef float    f32x4  __attribute__((ext_vector_type(4)));

// Zero-VGPR async global->LDS: cannot be sunk by the compiler.
#define GLL(gp, lp)                                                             \
    __builtin_amdgcn_global_load_lds(                                           \
        (const __attribute__((address_space(1))) uint32_t*)(gp),                \
        (__attribute__((address_space(3))) uint32_t*)(lp), 4, 0, 0)

// Raw barrier: lgkm drain only; GLLs stay in flight across it.
#define BARRIER()                                                               \
    __builtin_amdgcn_sched_barrier(0);                                          \
    asm volatile("s_waitcnt lgkmcnt(0)" ::: "memory");                          \
    __builtin_amdgcn_s_barrier();                                               \
    __builtin_amdgcn_sched_barrier(0);

// weight pack: [tap 9][msub 2][lane 64][e 8] fp16; co=(l&31)+32m, cin=8*(l>>5)+e
__global__ void wpack_kernel(const float* __restrict__ w, _Float16* __restrict__ wpk) {
    int idx = blockIdx.x * 256 + threadIdx.x;   // 0..9215
    if (idx >= 9 * 2 * 64 * 8) return;
    int e = idx & 7, l = (idx >> 3) & 63, m = (idx >> 9) & 1, t = idx >> 10;
    int co  = (l & 31) + 32 * m;
    int cin = 8 * (l >> 5) + e;
    wpk[idx] = (_Float16)w[((co * CIN + cin) * 3 + t / 3) * 3 + (t % 3)];
}

__device__ __forceinline__ float tanh_fast(float v) {
    float e = __expf(2.0f * v);
    return 1.0f - 2.0f * __builtin_amdgcn_rcpf(e + 1.0f);
}
__device__ __forceinline__ float min3f(float a, float b, float c) {
    return fminf(fminf(a, b), c);   // clang fuses to v_min3_f32
}

// 256 thr = 4 waves (2 px-slices x 2 rows). Block = (img, 64px col, 128-row
// half), 64 tiles x 2 out rows. Pipeline (2-tile lag, counted vmcnt only):
//   tile t: repack f32 rows 2t+6,7 -> f16 ring | issue GLL rows 2t+10,11
//           | compute rows 2t..2t+3 (f16 b128) | vmcnt(10) | raw barrier.
__global__ __launch_bounds__(256, 2) void conv_gll2_kernel(
        const float* __restrict__ x, const f16x8* __restrict__ wpk,
        const float* __restrict__ bias, float* __restrict__ out) {
    __shared__ float fring[FR * 1088];   // 34,816 B: [slot][px 68][cin^swz 16]
    __shared__ f16x8 hring[HRN * 136];   // 17,408 B: [slot][g 2][px 68]
    __shared__ float bias_lds[64];

    const int tid  = threadIdx.x;
    const int lane = tid & 63;
    const int wv   = tid >> 6;

    int bid = blockIdx.x;
    int nb  = (bid & 7) * 64 + (bid >> 3);     // 512 = 8*64 bijective XCD swizzle
    const int img  = nb >> 3;
    const int rem  = nb & 7;
    const int colb = rem & 3;                  // 64-px column
    const int half = rem >> 2;                 // 128-row half
    const int base = 64 * colb;
    const int R0   = 128 * half;

    const float* xb = x + (size_t)img * CIN * HWSZ;

    // ---- weights: full 64 cout -> 72 VGPRs ----
    f16x8 wreg[9][2];
#pragma unroll
    for (int t = 0; t < 9; ++t)
#pragma unroll
        for (int m = 0; m < 2; ++m)
            wreg[t][m] = wpk[(t * 2 + m) * 64 + lane];

    if (tid < 64) {
        int q = tid & 15, m = (tid >> 4) & 1, g = tid >> 5;
        bias_lds[tid] = bias[(q & 3) + 8 * (q >> 2) + 4 * g + 32 * m];
    }

    const int l31 = lane & 31;
    const int g2  = lane >> 5;

    // GLL lane decode: GLL j covers px quad [base+4j, +3] x 16 cin.
    // Source cin is XOR-swizzled by px so repack reads are 4-block-contiguous.
    const int pxq   = lane >> 4;                       // 0..3 px-in-quad
    const int cin_g = (lane & 15) ^ ((pxq & 3) << 2);  // swizzled source cin
    const int jb    = 8 * (wv & 1);                    // GLL j base (0 or 8)
    const int rsel  = wv >> 1;                         // staged row parity

    // this wave's 9 GLLs for row q (rel R0); j=8 is issued twice (benign dup)
    auto issue_half = [&](int q) {
        int grow = R0 + q; if (grow > 255) grow = 255;
        float* sp = &fring[(q & (FR - 1)) * 1088];
        const float* gr = xb + (size_t)cin_g * HWSZ + (size_t)grow * W;
#pragma unroll
        for (int i = 0; i < 9; ++i) {
            int j = jb + i;
            int px = base + 4 * j + pxq;
            if (px > 255) px = 255;
            GLL(gr + px, sp + j * 64);
        }
    };

    // one (px,g) repack unit of row absq: f32 [px][cin^s4] -> f16x8 [g][px]
    auto repack1 = [&](int absq, int remu) {
        int px = remu >> 1, g = remu & 1;
        const float* fp = &fring[(absq & (FR - 1)) * 1088 + px * 16];
        int s4 = (px & 3) << 2;
        f32x4 a = *(const f32x4*)(fp + ((8 * g) ^ s4));
        f32x4 b = *(const f32x4*)(fp + ((8 * g + 4) ^ s4));
        f16x8 h;
#pragma unroll
        for (int e = 0; e < 4; ++e) { h[e] = (_Float16)a[e]; h[e + 4] = (_Float16)b[e]; }
        hring[(absq & (HRN - 1)) * 136 + g * 68 + px] = h;
    };

    // ---- prologue: rows 0..7 staged+landed; repack 0..5; prime rows 8,9 ----
#pragma unroll
    for (int r = 0; r < 4; ++r) issue_half(2 * r + rsel);
    asm volatile("s_waitcnt vmcnt(0)" ::: "memory");
    BARRIER()
#pragma unroll
    for (int k = 0; k < 4; ++k) {              // 816 units = 6 rows x 136
        int u = tid + 256 * k;
        if (u < 816) repack1(u / 136, u % 136);
    }
    BARRIER()
    issue_half(8 + rsel);                      // rows 8,9 (9 GLLs/wave, loop cadence)

    const int s    = wv & 1;                   // px slice
    const int ro   = wv >> 1;                  // out row within tile
    const int foff = g2 * 68 + 32 * s + l31;
    const int opx  = base + 32 * s + l31;
    const size_t obase = (size_t)img * OH * OW;
    const f32x16* bp = (const f32x16*)(bias_lds + g2 * 32);
    const f32x16 cb0 = bp[0], cb1 = bp[1];     // hoisted bias C-fragments

#pragma unroll 1
    for (int t = 0; t < NT; ++t) {
        // 1. repack rows 2t+6, 2t+7 (272 units; landed: issued t-2, vmcnt'd t-1)
        {
            int u0 = tid;
            repack1(2 * t + 6 + (u0 >= 136), (u0 >= 136) ? u0 - 136 : u0);
            if (tid < 16) repack1(2 * t + 7, 120 + tid);
        }
        // 2. issue GLLs for rows 2t+10, 2t+11 (land during tile t+1)
        issue_half(2 * t + 10 + rsel);

        // 3. compute out row R0+2t+ro from f16 ring rows 2t+ro..+2
        f32x16 acc0, acc1;
#pragma unroll
        for (int kh = 0; kh < 3; ++kh) {
            const f16x8* rp = &hring[((2 * t + ro + kh) & (HRN - 1)) * 136 + foff];
            f16x8 f0 = rp[0], f1 = rp[1], f2 = rp[2];
            if (kh == 0) {
                acc0 = __builtin_amdgcn_mfma_f32_32x32x16_f16(wreg[0][0], f0, cb0, 0, 0, 0);
                acc1 = __builtin_amdgcn_mfma_f32_32x32x16_f16(wreg[0][1], f0, cb1, 0, 0, 0);
            } else {
                acc0 = __builtin_amdgcn_mfma_f32_32x32x16_f16(wreg[3 * kh][0], f0, acc0, 0, 0, 0);
                acc1 = __builtin_amdgcn_mfma_f32_32x32x16_f16(wreg[3 * kh][1], f0, acc1, 0, 0, 0);
            }
            acc0 = __builtin_amdgcn_mfma_f32_32x32x16_f16(wreg[3 * kh + 1][0], f1, acc0, 0, 0, 0);
            acc1 = __builtin_amdgcn_mfma_f32_32x32x16_f16(wreg[3 * kh + 1][1], f1, acc1, 0, 0, 0);
            acc0 = __builtin_amdgcn_mfma_f32_32x32x16_f16(wreg[3 * kh + 2][0], f2, acc0, 0, 0, 0);
            acc1 = __builtin_amdgcn_mfma_f32_32x32x16_f16(wreg[3 * kh + 2][1], f2, acc1, 0, 0, 0);
        }
        float mn = fminf(acc0[0], acc1[0]);
#pragma unroll
        for (int q = 1; q < 16; ++q) mn = min3f(acc0[q], acc1[q], mn);
        mn = fminf(mn, __shfl_xor(mn, 32));
        float t2 = tanh_fast(tanh_fast(mn));
        const int oh = R0 + 2 * t + ro;
        if (g2 == 0 && oh < OH && opx < OW)
            out[obase + (size_t)oh * OW + opx] = t2;

        // 4. counted wait: drains tile t-1's GLLs (FIFO), leaves ours in flight
        asm volatile("s_waitcnt vmcnt(10)" ::: "memory");
        // 5. raw barrier: repack writes + landing confirmation visible to all
        BARRIER()
    }
}

extern "C" void kernel_launch(void* const* d_in, const int* in_sizes, int n_in,
                              void* d_out, int out_size, void* d_ws, size_t ws_size,
                              hipStream_t stream) {
    const float* x    = (const float*)d_in[0];
    const float* w    = (const float*)d_in[1];
    const float* bias = (const float*)d_in[2];
    float* out = (float*)d_out;
    _Float16* wpk = (_Float16*)d_ws;   // 9216 fp16 = 18,432 B

    wpack_kernel<<<36, 256, 0, stream>>>(w, wpk);
    conv_gll2_kernel<<<512, 256, 0, stream>>>(x, (const f16x8*)wpk, bias, out);
}